// Round 2
// baseline (839.892 us; speedup 1.0000x reference)
//
#include <hip/hip_runtime.h>

// Problem constants (B=2, C=32, E=128, S=64, K=7, pad=3). All float32 I/O.
#define S 64
#define S2 4096
#define S3 262144
#define C 32
#define E 128
#define LN_EPS 1e-6f

// conv tile: D=8, H=4, W=64 (full row), 256 threads, 8 W-outputs/thread
#define TD 8
#define TH 4
#define HALO_D 14
#define HALO_H 10
#define HALO_W 72   // 70 valid + 2 pad for float4 alignment

// Depthwise 7x7x7 conv (+bias, masked). Writes masked y (zeros at inactive
// voxels) covering the FULL volume -> doubles as output-zeroing for d_out.
__global__ __launch_bounds__(256) void k_conv(
    const float* __restrict__ x,
    const int* __restrict__ mask,
    const float* __restrict__ wdw,
    const float* __restrict__ bdw,
    float* __restrict__ y)
{
    __shared__ float halo[HALO_D * HALO_H * HALO_W];   // 40.3 KB

    const int bx = blockIdx.x;            // 128 spatial tiles: 8 (D) x 16 (H)
    const int by = blockIdx.y;            // 64: b*C + c
    const int b  = by >> 5;
    const int c  = by & 31;
    const int d0 = (bx >> 4) * TD;
    const int h0 = (bx & 15) * TH;
    const int tid = threadIdx.x;

    const float* xc = x + (size_t)(b * C + c) * S3;
    const int* mb = mask + (size_t)b * S3;

    // stage masked input halo into LDS
    for (int idx = tid; idx < HALO_D * HALO_H * HALO_W; idx += 256) {
        int wl = idx % HALO_W;
        int r  = idx / HALO_W;
        int hy = r % HALO_H;
        int dz = r / HALO_H;
        int gw = wl - 3;
        int gh = h0 + hy - 3;
        int gd = d0 + dz - 3;
        float v = 0.f;
        if (wl < 70 && (unsigned)gw < 64u && (unsigned)gh < 64u && (unsigned)gd < 64u) {
            int off = gd * S2 + gh * S + gw;
            if (mb[off] != 0) v = xc[off];
        }
        halo[idx] = v;
    }
    __syncthreads();

    const int wq = tid & 7;  const int w0 = wq << 3;   // 8 outputs along W
    const int hh = (tid >> 3) & 3;
    const int dd = tid >> 5;

    float acc[8];
    #pragma unroll
    for (int j = 0; j < 8; ++j) acc[j] = 0.f;

    const float* wc = wdw + c * 343;

    for (int kd = 0; kd < 7; ++kd) {
        for (int kh = 0; kh < 7; ++kh) {
            const float* row = &halo[((dd + kd) * HALO_H + (hh + kh)) * HALO_W + w0];
            float4 a0 = *(const float4*)(row);
            float4 a1 = *(const float4*)(row + 4);
            float4 a2 = *(const float4*)(row + 8);
            float2 a3 = *(const float2*)(row + 12);
            float in14[14];
            in14[0] = a0.x; in14[1] = a0.y; in14[2]  = a0.z; in14[3]  = a0.w;
            in14[4] = a1.x; in14[5] = a1.y; in14[6]  = a1.z; in14[7]  = a1.w;
            in14[8] = a2.x; in14[9] = a2.y; in14[10] = a2.z; in14[11] = a2.w;
            in14[12] = a3.x; in14[13] = a3.y;
            const float* wr = wc + kd * 49 + kh * 7;   // wave-uniform -> s_load
            #pragma unroll
            for (int kw = 0; kw < 7; ++kw) {
                float wt = wr[kw];
                #pragma unroll
                for (int j = 0; j < 8; ++j) acc[j] += wt * in14[j + kw];
            }
        }
    }

    const int gd = d0 + dd, gh = h0 + hh;
    const float bb = bdw[c];
    const size_t obase = (size_t)(b * C + c) * S3 + gd * S2 + gh * S + w0;
    const int mbase = gd * S2 + gh * S + w0;

    float ov[8];
    #pragma unroll
    for (int j = 0; j < 8; ++j)
        ov[j] = (mb[mbase + j] != 0) ? (acc[j] + bb) : 0.f;
    *(float4*)(y + obase)     = make_float4(ov[0], ov[1], ov[2], ov[3]);
    *(float4*)(y + obase + 4) = make_float4(ov[4], ov[5], ov[6], ov[7]);
}

// Build compacted active-voxel list (order-free; values don't depend on order)
__global__ __launch_bounds__(256) void k_compact(
    const int* __restrict__ mask, int* __restrict__ counter, int* __restrict__ list)
{
    int v = blockIdx.x * 256 + threadIdx.x;
    if (mask[v] != 0) {
        int pos = atomicAdd(counter, 1);
        list[pos] = v;
    }
}

// Per-active-voxel: LN over C, expand+GELU, project, +residual.
// y lives in d_out; each thread reads then overwrites only its own 32 slots.
__global__ __launch_bounds__(256) void k_mlp(
    const float* __restrict__ x,
    const float* __restrict__ lng,
    const float* __restrict__ lnb,
    const float* __restrict__ w2,
    const float* __restrict__ b2v,
    const float* __restrict__ w3,
    const float* __restrict__ b3v,
    const int* __restrict__ mask,
    const int* __restrict__ counter,
    const int* __restrict__ list,
    float* __restrict__ out)
{
    int i = blockIdx.x * 256 + threadIdx.x;
    int v;
    if (list != nullptr) {
        int n = *counter;
        if (i >= n) return;
        v = list[i];
    } else {
        v = i;
        if (mask[v] == 0) return;
    }
    const int b = v >> 18;
    const int s = v & (S3 - 1);
    const size_t base = (size_t)b * C * S3 + s;

    float yv[32];
    #pragma unroll
    for (int c = 0; c < 32; ++c) yv[c] = out[base + (size_t)c * S3];

    float mu = 0.f;
    #pragma unroll
    for (int c = 0; c < 32; ++c) mu += yv[c];
    mu *= (1.f / 32.f);
    float var = 0.f;
    #pragma unroll
    for (int c = 0; c < 32; ++c) { float d = yv[c] - mu; var += d * d; }
    var *= (1.f / 32.f);
    const float rs = rsqrtf(var + LN_EPS);
    #pragma unroll
    for (int c = 0; c < 32; ++c)
        yv[c] = (yv[c] - mu) * rs * lng[c] + lnb[c];

    float o[32];
    #pragma unroll
    for (int c = 0; c < 32; ++c) o[c] = b3v[c];

    for (int e = 0; e < E; ++e) {
        float a = b2v[e];
        const float* w2r = w2 + e * 32;   // uniform -> scalar loads
        #pragma unroll
        for (int c = 0; c < 32; ++c) a += w2r[c] * yv[c];
        float g = 0.5f * a * (1.f + erff(a * 0.70710678118654752f));   // exact GELU
        #pragma unroll
        for (int c = 0; c < 32; ++c) o[c] += w3[c * 128 + e] * g;
    }

    #pragma unroll
    for (int c = 0; c < 32; ++c) {
        float xm = x[base + (size_t)c * S3];
        out[base + (size_t)c * S3] = xm + o[c];
    }
}

extern "C" void kernel_launch(void* const* d_in, const int* in_sizes, int n_in,
                              void* d_out, int out_size, void* d_ws, size_t ws_size,
                              hipStream_t stream)
{
    const float* x   = (const float*)d_in[0];
    const int*   m   = (const int*)d_in[1];
    const float* wdw = (const float*)d_in[2];
    const float* bdw = (const float*)d_in[3];
    const float* lng = (const float*)d_in[4];
    const float* lnb = (const float*)d_in[5];
    const float* w2  = (const float*)d_in[6];
    const float* b2v = (const float*)d_in[7];
    const float* w3  = (const float*)d_in[8];
    const float* b3v = (const float*)d_in[9];
    float* out = (float*)d_out;

    // conv writes full masked y straight into d_out (inactive voxels -> 0,
    // which is also the correct final output there). No d_out memset needed.
    k_conv<<<dim3(128, 64), 256, 0, stream>>>(x, m, wdw, bdw, out);

    // compaction needs only ~2.1 MB of ws; fall back to dense if unavailable
    const size_t need = 256 + (size_t)S3 * 2 * sizeof(int);
    if (ws_size >= need) {
        int* counter = (int*)d_ws;
        int* list    = (int*)((char*)d_ws + 256);
        hipMemsetAsync(counter, 0, 4, stream);
        k_compact<<<2048, 256, 0, stream>>>(m, counter, list);
        k_mlp<<<2048, 256, 0, stream>>>(x, lng, lnb, w2, b2v, w3, b3v,
                                        m, counter, list, out);
    } else {
        k_mlp<<<2048, 256, 0, stream>>>(x, lng, lnb, w2, b2v, w3, b3v,
                                        m, nullptr, nullptr, out);
    }
}

// Round 4
// 621.343 us; speedup vs baseline: 1.3517x; 1.3517x over previous
//
#include <hip/hip_runtime.h>

// Problem constants (B=2, C=32, E=128, S=64, K=7, pad=3). All float32 I/O.
#define S 64
#define S2 4096
#define S3 262144
#define NVOX (2 * S3)     // B * S^3 total voxels
#define C 32
#define E 128
#define LN_EPS 1e-6f

// conv tile: D=8, H=4, W=64 (full row), 256 threads, 8 W-outputs/thread
#define TD 8
#define TH 4
#define HD 14
#define HH 10
#define HWV 70      // valid halo cols
#define HSTR 73     // ODD row stride: bank = (9*row + 8*wq + i) mod 32 -> 2 lanes/bank (free)

// Depthwise 7x7x7 conv (+bias, masked). Writes masked y (zeros at inactive
// voxels) covering the FULL volume -> doubles as output-zeroing for d_out.
__global__ __launch_bounds__(256) void k_conv(
    const float* __restrict__ x,
    const int* __restrict__ mask,
    const float* __restrict__ wdw,
    const float* __restrict__ bdw,
    float* __restrict__ y)
{
    __shared__ float halo[HD * HH * HSTR];   // 40.88 KB -> 3 blocks/CU

    const int bx = blockIdx.x;            // 128 spatial tiles: 8 (D) x 16 (H)
    const int by = blockIdx.y;            // 64: b*C + c
    const int b  = by >> 5;
    const int c  = by & 31;
    const int d0 = (bx >> 4) * TD;
    const int h0 = (bx & 15) * TH;
    const int tid = threadIdx.x;

    const float* xc = x + (size_t)(b * C + c) * S3;
    const int* mb = mask + (size_t)b * S3;

    // stage masked input halo into LDS (b32 stores, odd stride -> conflict-free)
    for (int t = tid; t < HD * HH * 72; t += 256) {
        int r   = t / 72;          // const-div -> magic mul
        int cln = t - r * 72;
        int hy = r % HH;
        int dz = r / HH;
        int gw = cln - 3;
        int gh = h0 + hy - 3;
        int gd = d0 + dz - 3;
        if (cln < HWV) {
            float v = 0.f;
            if ((unsigned)gw < 64u && (unsigned)gh < 64u && (unsigned)gd < 64u) {
                int off = gd * S2 + gh * S + gw;
                if (mb[off] != 0) v = xc[off];
            }
            halo[r * HSTR + cln] = v;
        }
    }
    __syncthreads();

    const int wq = tid & 7;  const int w0 = wq << 3;   // 8 outputs along W
    const int hh = (tid >> 3) & 3;
    const int dd = tid >> 5;

    float acc[8];
    #pragma unroll
    for (int j = 0; j < 8; ++j) acc[j] = 0.f;

    const float* wc = wdw + c * 343;

    for (int kd = 0; kd < 7; ++kd) {
        #pragma unroll
        for (int kh = 0; kh < 7; ++kh) {
            const float* row = &halo[((dd + kd) * HH + (hh + kh)) * HSTR + w0];
            float in14[14];
            #pragma unroll
            for (int i = 0; i < 14; ++i) in14[i] = row[i];   // b32, 2-way max
            const float* wr = wc + kd * 49 + kh * 7;         // wave-uniform -> s_load
            #pragma unroll
            for (int kw = 0; kw < 7; ++kw) {
                float wt = wr[kw];
                #pragma unroll
                for (int j = 0; j < 8; ++j) acc[j] = fmaf(wt, in14[j + kw], acc[j]);
            }
        }
    }

    const int gd = d0 + dd, gh = h0 + hh;
    const float bb = bdw[c];
    const size_t obase = (size_t)(b * C + c) * S3 + gd * S2 + gh * S + w0;
    const int mbase = gd * S2 + gh * S + w0;

    float ov[8];
    #pragma unroll
    for (int j = 0; j < 8; ++j)
        ov[j] = (mb[mbase + j] != 0) ? (acc[j] + bb) : 0.f;
    *(float4*)(y + obase)     = make_float4(ov[0], ov[1], ov[2], ov[3]);
    *(float4*)(y + obase + 4) = make_float4(ov[4], ov[5], ov[6], ov[7]);
}

// ---- sorted compaction over ALL NVOX voxels: count -> scan -> scatter
// 2048 blocks x 256 threads cover B*S^3 = 524288 voxels.
__global__ __launch_bounds__(256) void k_count(
    const int* __restrict__ mask, int* __restrict__ bcnt)
{
    int v = blockIdx.x * 256 + threadIdx.x;
    int act = (mask[v] != 0) ? 1 : 0;
    unsigned long long ball = __ballot(act);
    __shared__ int wsum[4];
    int lane = threadIdx.x & 63, wid = threadIdx.x >> 6;
    if (lane == 0) wsum[wid] = __popcll(ball);
    __syncthreads();
    if (threadIdx.x == 0)
        bcnt[blockIdx.x] = wsum[0] + wsum[1] + wsum[2] + wsum[3];
}

__global__ __launch_bounds__(256) void k_scan(
    const int* __restrict__ bcnt, int* __restrict__ bbase, int* __restrict__ ntot)
{
    int t = threadIdx.x;                 // 256 threads, 8 counts each (2048 blocks)
    int cv[8]; int s = 0;
    #pragma unroll
    for (int j = 0; j < 8; ++j) { cv[j] = bcnt[t * 8 + j]; s += cv[j]; }
    int lane = t & 63, wid = t >> 6;
    int x = s;                           // inclusive wave scan
    #pragma unroll
    for (int off = 1; off < 64; off <<= 1) {
        int yv = __shfl_up(x, off, 64);
        if (lane >= off) x += yv;
    }
    __shared__ int wtot[4];
    if (lane == 63) wtot[wid] = x;
    __syncthreads();
    int wbase = 0;
    for (int w = 0; w < wid; ++w) wbase += wtot[w];
    int run = wbase + x - s;             // exclusive prefix for this thread's first block
    #pragma unroll
    for (int j = 0; j < 8; ++j) { bbase[t * 8 + j] = run; run += cv[j]; }
    if (t == 255) *ntot = run;
}

__global__ __launch_bounds__(256) void k_scatter(
    const int* __restrict__ mask, const int* __restrict__ bbase,
    int* __restrict__ list)
{
    int v = blockIdx.x * 256 + threadIdx.x;
    int act = (mask[v] != 0) ? 1 : 0;
    unsigned long long ball = __ballot(act);
    int lane = threadIdx.x & 63, wid = threadIdx.x >> 6;
    __shared__ int wcnt[4];
    if (lane == 0) wcnt[wid] = __popcll(ball);
    __syncthreads();
    int base = bbase[blockIdx.x];
    for (int w = 0; w < wid; ++w) base += wcnt[w];
    int pre = __popcll(ball & ((1ull << lane) - 1ull));
    if (act) list[base + pre] = v;       // globally sorted: blocks & lanes in order
}

// Per-active-voxel: LN over C, expand+GELU, project, +residual.
// y lives in d_out; each thread reads then overwrites only its own 32 slots.
__global__ __launch_bounds__(256) void k_mlp(
    const float* __restrict__ x,
    const float* __restrict__ lng,
    const float* __restrict__ lnb,
    const float* __restrict__ w2,
    const float* __restrict__ b2v,
    const float* __restrict__ w3,
    const float* __restrict__ b3v,
    const int* __restrict__ mask,
    const int* __restrict__ ntot,
    const int* __restrict__ list,
    float* __restrict__ out)
{
    int i = blockIdx.x * 256 + threadIdx.x;
    int v;
    if (list != nullptr) {
        if (i >= *ntot) return;
        v = list[i];                     // sorted -> near-coalesced gathers
    } else {
        v = i;
        if (mask[v] == 0) return;
    }
    const int b = v >> 18;
    const int s = v & (S3 - 1);
    const size_t base = (size_t)b * C * S3 + s;

    float yv[32];
    #pragma unroll
    for (int c = 0; c < 32; ++c) yv[c] = out[base + (size_t)c * S3];

    float mu = 0.f;
    #pragma unroll
    for (int c = 0; c < 32; ++c) mu += yv[c];
    mu *= (1.f / 32.f);
    float var = 0.f;
    #pragma unroll
    for (int c = 0; c < 32; ++c) { float d = yv[c] - mu; var += d * d; }
    var *= (1.f / 32.f);
    const float rs = rsqrtf(var + LN_EPS);
    #pragma unroll
    for (int c = 0; c < 32; ++c)
        yv[c] = (yv[c] - mu) * rs * lng[c] + lnb[c];

    float o[32];
    #pragma unroll
    for (int c = 0; c < 32; ++c) o[c] = b3v[c];

    for (int e = 0; e < E; ++e) {
        float a = b2v[e];
        const float* w2r = w2 + e * 32;   // uniform -> scalar loads
        #pragma unroll
        for (int c = 0; c < 32; ++c) a += w2r[c] * yv[c];
        float g = 0.5f * a * (1.f + erff(a * 0.70710678118654752f));   // exact GELU
        #pragma unroll
        for (int c = 0; c < 32; ++c) o[c] += w3[c * 128 + e] * g;
    }

    #pragma unroll
    for (int c = 0; c < 32; ++c) {
        float xm = x[base + (size_t)c * S3];
        out[base + (size_t)c * S3] = xm + o[c];
    }
}

extern "C" void kernel_launch(void* const* d_in, const int* in_sizes, int n_in,
                              void* d_out, int out_size, void* d_ws, size_t ws_size,
                              hipStream_t stream)
{
    const float* x   = (const float*)d_in[0];
    const int*   m   = (const int*)d_in[1];
    const float* wdw = (const float*)d_in[2];
    const float* bdw = (const float*)d_in[3];
    const float* lng = (const float*)d_in[4];
    const float* lnb = (const float*)d_in[5];
    const float* w2  = (const float*)d_in[6];
    const float* b2v = (const float*)d_in[7];
    const float* w3  = (const float*)d_in[8];
    const float* b3v = (const float*)d_in[9];
    float* out = (float*)d_out;

    // conv writes full masked y straight into d_out (inactive voxels -> 0,
    // which is also the correct final output there). No d_out memset needed.
    k_conv<<<dim3(128, 64), 256, 0, stream>>>(x, m, wdw, bdw, out);

    // ws layout: [ntot:4][pad][bcnt:8KB][bbase:8KB][list:2MB]
    const size_t need = 256 + 8192 + 8192 + (size_t)NVOX * sizeof(int);
    if (ws_size >= need) {
        int* ntot  = (int*)d_ws;
        int* bcnt  = (int*)((char*)d_ws + 256);
        int* bbase = (int*)((char*)d_ws + 256 + 8192);
        int* list  = (int*)((char*)d_ws + 256 + 16384);
        k_count  <<<2048, 256, 0, stream>>>(m, bcnt);
        k_scan   <<<1,    256, 0, stream>>>(bcnt, bbase, ntot);
        k_scatter<<<2048, 256, 0, stream>>>(m, bbase, list);
        k_mlp<<<2048, 256, 0, stream>>>(x, lng, lnb, w2, b2v, w3, b3v,
                                        m, ntot, list, out);
    } else {
        k_mlp<<<2048, 256, 0, stream>>>(x, lng, lnb, w2, b2v, w3, b3v,
                                        m, nullptr, nullptr, out);
    }
}